// Round 8
// baseline (305.245 us; speedup 1.0000x reference)
//
#include <hip/hip_runtime.h>
#include <math.h>

// Problem constants (fixed by reference): B=4, S=2048, D=512, H=8, R=8, dk=64
#define B_ 4
#define S_ 2048
#define D_ 512
#define H_ 8
#define R_ 8
#define DK_ 64
#define NEDGE (B_*H_*2*R_*S_)   // 1,048,576
#define ELLCAP 64               // max in-degree slots; Poisson(15) tail ~2e-8

typedef __attribute__((ext_vector_type(8))) short bf16x8;
typedef __attribute__((ext_vector_type(8))) unsigned short ushort8_t;
typedef __attribute__((ext_vector_type(4))) float f32x4;

#define AS1q const __attribute__((address_space(1)))
#define AS3q __attribute__((address_space(3)))

__device__ inline unsigned short f2bf(float f) {
    unsigned u = __builtin_bit_cast(unsigned, f);
    u += 0x7fffu + ((u >> 16) & 1u);   // RNE (no NaN inputs here)
    return (unsigned short)(u >> 16);
}
__device__ inline float bf2f(unsigned short u) {
    return __builtin_bit_cast(float, ((unsigned)u) << 16);
}

// ---------------- fused prep: qkv+W converts + deg zero ---------------------
__global__ __launch_bounds__(256) void prep(
    const float* __restrict__ query, const float* __restrict__ key,
    const float* __restrict__ value,
    const float* __restrict__ Wq, const float* __restrict__ Wk,
    const float* __restrict__ Wv, const float* __restrict__ Wo,
    unsigned short* __restrict__ qc, unsigned short* __restrict__ kc,
    unsigned short* __restrict__ vc,
    unsigned short* __restrict__ wqb, unsigned short* __restrict__ wkb,
    unsigned short* __restrict__ wvb, unsigned short* __restrict__ wob,
    int* __restrict__ deg)
{
    int bid = blockIdx.x;
    if (bid < 12288) {
        int z = bid >> 12;                 // 0..2
        const float* x = (z == 0) ? query : (z == 1) ? key : value;
        unsigned short* y = (z == 0) ? qc : (z == 1) ? kc : vc;
        size_t i = ((size_t)(bid & 4095) * 256 + threadIdx.x) * 4;
        float4 v = *(const float4*)&x[i];
        *(ushort4*)&y[i] = make_ushort4(f2bf(v.x), f2bf(v.y), f2bf(v.z), f2bf(v.w));
    } else if (bid < 13312) {
        int r = bid - 12288;
        int z = r >> 8;                    // 0..3
        const float* x = (z == 0) ? Wq : (z == 1) ? Wk : (z == 2) ? Wv : Wo;
        unsigned short* y = (z == 0) ? wqb : (z == 1) ? wkb : (z == 2) ? wvb : wob;
        size_t i = ((size_t)(r & 255) * 256 + threadIdx.x) * 4;
        float4 v = *(const float4*)&x[i];
        *(ushort4*)&y[i] = make_ushort4(f2bf(v.x), f2bf(v.y), f2bf(v.z), f2bf(v.w));
    } else {
        int r = bid - 13312;
        *(int4*)&deg[((size_t)r * 256 + threadIdx.x) * 4] = make_int4(0, 0, 0, 0);
    }
}

// ---------------- bf16 GEMM, m97-style: global_load_lds + XOR-swizzled LDS --
template<int TN>
__global__ __launch_bounds__(256) void gemm_bf16(
    const unsigned short* __restrict__ A0, const unsigned short* __restrict__ A1,
    const unsigned short* __restrict__ A2,
    const unsigned short* __restrict__ W0, const unsigned short* __restrict__ W1,
    const unsigned short* __restrict__ W2,
    const float* __restrict__ bi0, const float* __restrict__ bi1, const float* __restrict__ bi2,
    unsigned short* __restrict__ C0, unsigned short* __restrict__ C1,
    unsigned short* __restrict__ C2,
    float* __restrict__ Cf, int a_bhsd)
{
    constexpr int NFR = TN / 32;           // B frags per wave (4 or 2)
    __shared__ unsigned short As[128 * 64];
    __shared__ unsigned short Bs[TN * 64];
    const int z = blockIdx.z;
    const unsigned short* A = (z == 0) ? A0 : (z == 1) ? A1 : A2;
    const unsigned short* W = (z == 0) ? W0 : (z == 1) ? W1 : W2;
    const float* bias        = (z == 0) ? bi0 : (z == 1) ? bi1 : bi2;
    unsigned short* C        = (z == 0) ? C0 : (z == 1) ? C1 : C2;

    const int t    = threadIdx.x;
    const int lane = t & 63;
    const int w    = t >> 6;
    const int wm   = w >> 1, wn = w & 1;
    const int m0   = blockIdx.x * 128;
    const int n0   = blockIdx.y * TN;

    const int lr    = lane >> 3;           // row within 8-row stage chunk
    const int cglob = (lane & 7) ^ lr;     // swizzled global source chunk

    f32x4 acc[4][NFR] = {};

    for (int kk = 0; kk < D_; kk += 64) {
        #pragma unroll
        for (int i = 0; i < 4; ++i) {
            int rowl = w * 32 + i * 8;         // wave-uniform LDS row base
            int m = m0 + rowl + lr;
            const unsigned short* ga;
            if (a_bhsd) {
                int b = m >> 11, s = m & (S_ - 1), h = kk >> 6;
                ga = A + ((((size_t)b * H_ + h) * S_ + s) << 6) + cglob * 8;
            } else {
                ga = A + (size_t)m * D_ + kk + cglob * 8;
            }
            __builtin_amdgcn_global_load_lds((AS1q unsigned*)ga,
                (AS3q unsigned*)(As + rowl * 64), 16, 0, 0);
        }
        #pragma unroll
        for (int i = 0; i < TN / 32; ++i) {
            int rowl = w * (TN / 4) + i * 8;
            const unsigned short* gb =
                W + (size_t)(n0 + rowl + lr) * D_ + kk + cglob * 8;
            __builtin_amdgcn_global_load_lds((AS1q unsigned*)gb,
                (AS3q unsigned*)(Bs + rowl * 64), 16, 0, 0);
        }
        __syncthreads();

        #pragma unroll
        for (int ks = 0; ks < 64; ks += 32) {
            const int c0 = ks >> 3;            // 0 or 4
            bf16x8 af[4], bfr[NFR];
            #pragma unroll
            for (int mi = 0; mi < 4; ++mi) {
                int row = wm * 64 + mi * 16 + (lane & 15);
                int cp  = (c0 + (lane >> 4)) ^ (lane & 7);
                af[mi] = *(const bf16x8*)&As[row * 64 + cp * 8];
            }
            #pragma unroll
            for (int nj = 0; nj < NFR; ++nj) {
                int row = wn * (TN / 2) + nj * 16 + (lane & 15);
                int cp  = (c0 + (lane >> 4)) ^ (lane & 7);
                bfr[nj] = *(const bf16x8*)&Bs[row * 64 + cp * 8];
            }
            #pragma unroll
            for (int mi = 0; mi < 4; ++mi)
                #pragma unroll
                for (int nj = 0; nj < NFR; ++nj)
                    acc[mi][nj] = __builtin_amdgcn_mfma_f32_16x16x32_bf16(af[mi], bfr[nj], acc[mi][nj], 0, 0, 0);
        }
        __syncthreads();
    }

    // epilogue: C/D layout col = lane&15, row = (lane>>4)*4 + reg
    #pragma unroll
    for (int mi = 0; mi < 4; ++mi) {
        #pragma unroll
        for (int nj = 0; nj < NFR; ++nj) {
            #pragma unroll
            for (int r = 0; r < 4; ++r) {
                int m = m0 + wm * 64 + mi * 16 + (lane >> 4) * 4 + r;
                int n = n0 + wn * (TN / 2) + nj * 16 + (lane & 15);
                float val = acc[mi][nj][r] + bias[n];
                if (Cf) {
                    Cf[(size_t)m * D_ + n] = val;
                } else {
                    int b = m >> 11, s = m & (S_ - 1);
                    int h = n >> 6,  d = n & 63;
                    C[((((size_t)b * H_ + h) * S_ + s) << 6) + d] = f2bf(val);
                }
            }
        }
    }
}

// ---------------- ELL build: XCD-local edge assignment ----------------------
// Edges of bh only touch deg/ell rows of bh. Blocks with blockIdx&7 == xcd
// handle bh in {xcd*4..xcd*4+3}: all stores/atomics stay in that XCD's L2
// slice (deg 32 KB + ell 2 MB per XCD) -> no cross-XCD line ping-pong.
__global__ __launch_bounds__(256) void fill_ell(
    const int* __restrict__ start_nodes, const int* __restrict__ end_nodes,
    int* __restrict__ deg, unsigned short* __restrict__ ell)
{
    int raw = blockIdx.x;             // 4096 blocks
    int xcd = raw & 7;
    int loc = raw >> 3;               // 0..511
    int bh  = xcd * 4 + (loc >> 7);   // 4 bh per XCD
    int e   = (loc & 127) * 256 + threadIdx.x;   // 0..32767 within bh
    int r2  = e >> 11;
    int s   = e & (S_ - 1);
    if (r2 == 0) return;
    int r  = r2 & 7;
    int idx = (bh * R_ + r) * S_ + s;
    int sn = start_nodes[idx];
    if (sn == -1) return;
    int en = end_nodes[idx];
    int dst = (r2 < R_) ? en : sn;
    int ki  = (r2 < R_) ? sn : en;
    int g = bh * S_ + dst;
    int pos = atomicAdd(&deg[g], 1);
    if (pos < ELLCAP)
        ell[(size_t)g * ELLCAP + pos] = (unsigned short)((r2 << 11) | ki);
}

// ---------------- fused score+softmax+aggregate -----------------------------
// One wave per dst node; 8 edges/iteration, 8 lanes/edge, 8 dk elems/lane.
// Algebraic split: score = (q+rq_r2)·k + u_r2 where u_r2 = q·rk_r2 is
// precomputed per wave (16 dots, 2 per 8-lane group) -> rk leaves the loop.
__global__ __launch_bounds__(256) void edge_gather(
    const unsigned short* __restrict__ q, const unsigned short* __restrict__ k_,
    const unsigned short* __restrict__ v_,
    const float* __restrict__ rel_q, const float* __restrict__ rel_k,
    const float* __restrict__ rel_v,
    const int* __restrict__ deg, const unsigned short* __restrict__ ell,
    unsigned short* __restrict__ attn)
{
    __shared__ float u_sh[4][16];
    int raw = blockIdx.x;
    int xcd = raw & 7;
    int loc = raw >> 3;                 // 0..2047
    int bh  = xcd * 4 + (loc >> 9);     // 4 bh per XCD (k+v slice L2-resident)
    int wid = threadIdx.x >> 6;
    int dst = (loc & 511) * 4 + wid;
    int lane = threadIdx.x & 63;
    int grp = lane >> 3;                // edge slot within group-of-8
    int sub = lane & 7;                 // dk chunk (8 elems)
    int h = bh & 7;
    int g = bh * S_ + dst;
    size_t node_base = ((size_t)bh << 11);

    ushort8_t q8 = *(const ushort8_t*)&q[((node_base + dst) << 6) + sub * 8];
    float qv[8];
    #pragma unroll
    for (int i = 0; i < 8; ++i) qv[i] = bf2f(q8[i]);

    // u[r2] = q . rel_k[r2]; each group computes r2 = grp*2, grp*2+1
    #pragma unroll
    for (int rr = 0; rr < 2; ++rr) {
        int r2p = grp * 2 + rr;
        int roff = (((h << 4) + r2p) << 6) + sub * 8;
        float rkv[8];
        *(float4*)&rkv[0] = *(const float4*)&rel_k[roff];
        *(float4*)&rkv[4] = *(const float4*)&rel_k[roff + 4];
        float u = 0.f;
        #pragma unroll
        for (int i = 0; i < 8; ++i) u = fmaf(qv[i], rkv[i], u);
        u += __shfl_xor(u, 1);
        u += __shfl_xor(u, 2);
        u += __shfl_xor(u, 4);
        if (sub == 0) u_sh[wid][r2p] = u;
    }
    // same-wave LDS RAW: compiler-inserted lgkmcnt wait, no barrier needed

    int n = deg[g];
    if (n > ELLCAP) n = ELLCAP;
    int d_all = (int)ell[(size_t)g * ELLCAP + lane];   // full row, 128 B coalesced

    float den = 0.f;
    float o[8] = {};
    #pragma unroll 2
    for (int j = 0; j < n; j += 8) {
        int slot = j + grp;
        int d = __shfl(d_all, slot);
        bool valid = slot < n;
        int ki = d & (S_ - 1);
        int r2 = (d >> 11) & 15;
        size_t koff = ((node_base + ki) << 6) + sub * 8;
        int roff = (((h << 4) + r2) << 6) + sub * 8;
        ushort8_t k8 = *(const ushort8_t*)&k_[koff];
        float rqv[8], rvv[8];
        *(float4*)&rqv[0] = *(const float4*)&rel_q[roff];
        *(float4*)&rqv[4] = *(const float4*)&rel_q[roff + 4];
        float p = 0.f;
        #pragma unroll
        for (int i = 0; i < 8; ++i)
            p = fmaf(bf2f(k8[i]), qv[i] + rqv[i], p);
        p += __shfl_xor(p, 1);
        p += __shfl_xor(p, 2);
        p += __shfl_xor(p, 4);
        p += u_sh[wid][r2];
        float sf = valid ? __expf(p * (1.0f / 24.0f)) : 0.f;   // 3*sqrt(64)=24
        ushort8_t v8 = *(const ushort8_t*)&v_[koff];
        *(float4*)&rvv[0] = *(const float4*)&rel_v[roff];
        *(float4*)&rvv[4] = *(const float4*)&rel_v[roff + 4];
        den += sf;
        #pragma unroll
        for (int i = 0; i < 8; ++i)
            o[i] = fmaf(sf, bf2f(v8[i]) + rvv[i], o[i]);
    }
    // cross-group reduction (xor 8,16,32 preserves sub)
    den += __shfl_xor(den, 8); den += __shfl_xor(den, 16); den += __shfl_xor(den, 32);
    #pragma unroll
    for (int i = 0; i < 8; ++i) {
        o[i] += __shfl_xor(o[i], 8);
        o[i] += __shfl_xor(o[i], 16);
        o[i] += __shfl_xor(o[i], 32);
    }
    if (grp == 0) {
        float inv = (den > 0.f) ? 1.0f / den : 0.f;
        ushort8_t r;
        #pragma unroll
        for (int i = 0; i < 8; ++i) r[i] = f2bf(o[i] * inv);
        *(ushort8_t*)&attn[((node_base + dst) << 6) + sub * 8] = r;
    }
}

extern "C" void kernel_launch(void* const* d_in, const int* in_sizes, int n_in,
                              void* d_out, int out_size, void* d_ws, size_t ws_size,
                              hipStream_t stream) {
    const float* query = (const float*)d_in[0];
    const float* key   = (const float*)d_in[1];
    const float* value = (const float*)d_in[2];
    const int* start_nodes = (const int*)d_in[3];
    const int* end_nodes   = (const int*)d_in[4];
    const float* rel_q = (const float*)d_in[5];
    const float* rel_k = (const float*)d_in[6];
    const float* rel_v = (const float*)d_in[7];
    const float* Wq = (const float*)d_in[8];
    const float* bq = (const float*)d_in[9];
    const float* Wk = (const float*)d_in[10];
    const float* bk = (const float*)d_in[11];
    const float* Wv = (const float*)d_in[12];
    const float* bv = (const float*)d_in[13];
    const float* Wo = (const float*)d_in[14];
    const float* bo = (const float*)d_in[15];
    float* out = (float*)d_out;

    const size_t NQ = (size_t)B_ * H_ * S_ * DK_;   // 4,194,304
    const size_t NW = (size_t)D_ * D_;              // 262,144
    const size_t NG = (size_t)B_ * H_ * S_;         // 65,536 nodes
    unsigned short* p = (unsigned short*)d_ws;
    unsigned short* qc = p;            p += NQ;
    unsigned short* kc = p;            p += NQ;
    unsigned short* vc = p;            p += NQ;
    unsigned short* q  = p;            p += NQ;
    unsigned short* k  = p;            p += NQ;
    unsigned short* v  = p;            p += NQ;
    unsigned short* attn = p;          p += NQ;
    unsigned short* wqb = p;           p += NW;
    unsigned short* wkb = p;           p += NW;
    unsigned short* wvb = p;           p += NW;
    unsigned short* wob = p;           p += NW;
    unsigned short* ell = p;           p += NG * ELLCAP;   // 8 MB
    int* deg = (int*)p;

    // 1) fused converts + deg zero (one dispatch)
    prep<<<13376, 256, 0, stream>>>(query, key, value, Wq, Wk, Wv, Wo,
                                    qc, kc, vc, wqb, wkb, wvb, wob, deg);

    // 2) ELL inversion (XCD-local)
    fill_ell<<<NEDGE / 256, 256, 0, stream>>>(start_nodes, end_nodes, deg, ell);

    // 3) fused QKV projection (128x128 tiles, 768 blocks)
    dim3 ggrid(B_ * S_ / 128, D_ / 128, 3);
    gemm_bf16<128><<<ggrid, 256, 0, stream>>>(qc, kc, vc, wqb, wkb, wvb, bq, bk, bv,
                                              q, k, v, nullptr, 0);

    // 4) fused attention (gather form, ELL)
    edge_gather<<<(B_ * H_ * S_) / 4, 256, 0, stream>>>(
        q, k, v, rel_q, rel_k, rel_v, deg, ell, attn);

    // 5) output projection (128x64 tiles -> 512 blocks = 2/CU, fp32 out)
    dim3 ogrid(B_ * S_ / 128, D_ / 64, 1);
    gemm_bf16<64><<<ogrid, 256, 0, stream>>>(attn, attn, attn, wob, wob, wob, bo, bo, bo,
                                             nullptr, nullptr, nullptr, out, 1);
}

// Round 9
// 237.645 us; speedup vs baseline: 1.2845x; 1.2845x over previous
//
#include <hip/hip_runtime.h>
#include <math.h>

// Problem constants (fixed by reference): B=4, S=2048, D=512, H=8, R=8, dk=64
#define B_ 4
#define S_ 2048
#define D_ 512
#define H_ 8
#define R_ 8
#define DK_ 64
#define NEDGE (B_*H_*2*R_*S_)   // 1,048,576
#define EPB   (2*R_*S_)         // 32768 edges per (b,h)
#define ELLCAP 64               // max in-degree slots; Poisson(15) tail ~2e-8

typedef __attribute__((ext_vector_type(8))) short bf16x8;
typedef __attribute__((ext_vector_type(8))) unsigned short ushort8_t;
typedef __attribute__((ext_vector_type(4))) float f32x4;

#define AS1q const __attribute__((address_space(1)))
#define AS3q __attribute__((address_space(3)))

__device__ inline unsigned short f2bf(float f) {
    unsigned u = __builtin_bit_cast(unsigned, f);
    u += 0x7fffu + ((u >> 16) & 1u);   // RNE (no NaN inputs here)
    return (unsigned short)(u >> 16);
}
__device__ inline float bf2f(unsigned short u) {
    return __builtin_bit_cast(float, ((unsigned)u) << 16);
}

// ---------------- fused prep: qkv + W + rel converts ------------------------
// blocks 0..12287: q/k/v (3 x 4096); 12288..13311: W (4 x 256);
// 13312..13335: rel_q/rel_k/rel_v (3 x 8).
__global__ __launch_bounds__(256) void prep(
    const float* __restrict__ query, const float* __restrict__ key,
    const float* __restrict__ value,
    const float* __restrict__ Wq, const float* __restrict__ Wk,
    const float* __restrict__ Wv, const float* __restrict__ Wo,
    const float* __restrict__ rel_q, const float* __restrict__ rel_k,
    const float* __restrict__ rel_v,
    unsigned short* __restrict__ qc, unsigned short* __restrict__ kc,
    unsigned short* __restrict__ vc,
    unsigned short* __restrict__ wqb, unsigned short* __restrict__ wkb,
    unsigned short* __restrict__ wvb, unsigned short* __restrict__ wob,
    unsigned short* __restrict__ rqb, unsigned short* __restrict__ rkb,
    unsigned short* __restrict__ rvb)
{
    int bid = blockIdx.x;
    const float* x;
    unsigned short* y;
    size_t i;
    if (bid < 12288) {
        int z = bid >> 12;                 // 0..2
        x = (z == 0) ? query : (z == 1) ? key : value;
        y = (z == 0) ? qc : (z == 1) ? kc : vc;
        i = ((size_t)(bid & 4095) * 256 + threadIdx.x) * 4;
    } else if (bid < 13312) {
        int r = bid - 12288;
        int z = r >> 8;                    // 0..3
        x = (z == 0) ? Wq : (z == 1) ? Wk : (z == 2) ? Wv : Wo;
        y = (z == 0) ? wqb : (z == 1) ? wkb : (z == 2) ? wvb : wob;
        i = ((size_t)(r & 255) * 256 + threadIdx.x) * 4;
    } else {
        int r = bid - 13312;               // 0..23
        int z = r >> 3;                    // 0..2
        x = (z == 0) ? rel_q : (z == 1) ? rel_k : rel_v;
        y = (z == 0) ? rqb : (z == 1) ? rkb : rvb;
        i = ((size_t)(r & 7) * 256 + threadIdx.x) * 4;
    }
    float4 v = *(const float4*)&x[i];
    *(ushort4*)&y[i] = make_ushort4(f2bf(v.x), f2bf(v.y), f2bf(v.z), f2bf(v.w));
}

// ---------------- bf16 GEMM, m97-style: global_load_lds + XOR-swizzled LDS --
template<int TN>
__global__ __launch_bounds__(256) void gemm_bf16(
    const unsigned short* __restrict__ A0, const unsigned short* __restrict__ A1,
    const unsigned short* __restrict__ A2,
    const unsigned short* __restrict__ W0, const unsigned short* __restrict__ W1,
    const unsigned short* __restrict__ W2,
    const float* __restrict__ bi0, const float* __restrict__ bi1, const float* __restrict__ bi2,
    unsigned short* __restrict__ C0, unsigned short* __restrict__ C1,
    unsigned short* __restrict__ C2,
    float* __restrict__ Cf, int a_bhsd)
{
    constexpr int NFR = TN / 32;           // B frags per wave (4 or 2)
    __shared__ unsigned short As[128 * 64];
    __shared__ unsigned short Bs[TN * 64];
    const int z = blockIdx.z;
    const unsigned short* A = (z == 0) ? A0 : (z == 1) ? A1 : A2;
    const unsigned short* W = (z == 0) ? W0 : (z == 1) ? W1 : W2;
    const float* bias        = (z == 0) ? bi0 : (z == 1) ? bi1 : bi2;
    unsigned short* C        = (z == 0) ? C0 : (z == 1) ? C1 : C2;

    const int t    = threadIdx.x;
    const int lane = t & 63;
    const int w    = t >> 6;
    const int wm   = w >> 1, wn = w & 1;
    const int m0   = blockIdx.x * 128;
    const int n0   = blockIdx.y * TN;

    const int lr    = lane >> 3;           // row within 8-row stage chunk
    const int cglob = (lane & 7) ^ lr;     // swizzled global source chunk

    f32x4 acc[4][NFR] = {};

    for (int kk = 0; kk < D_; kk += 64) {
        #pragma unroll
        for (int i = 0; i < 4; ++i) {
            int rowl = w * 32 + i * 8;         // wave-uniform LDS row base
            int m = m0 + rowl + lr;
            const unsigned short* ga;
            if (a_bhsd) {
                int b = m >> 11, s = m & (S_ - 1), h = kk >> 6;
                ga = A + ((((size_t)b * H_ + h) * S_ + s) << 6) + cglob * 8;
            } else {
                ga = A + (size_t)m * D_ + kk + cglob * 8;
            }
            __builtin_amdgcn_global_load_lds((AS1q unsigned*)ga,
                (AS3q unsigned*)(As + rowl * 64), 16, 0, 0);
        }
        #pragma unroll
        for (int i = 0; i < TN / 32; ++i) {
            int rowl = w * (TN / 4) + i * 8;
            const unsigned short* gb =
                W + (size_t)(n0 + rowl + lr) * D_ + kk + cglob * 8;
            __builtin_amdgcn_global_load_lds((AS1q unsigned*)gb,
                (AS3q unsigned*)(Bs + rowl * 64), 16, 0, 0);
        }
        __syncthreads();

        #pragma unroll
        for (int ks = 0; ks < 64; ks += 32) {
            const int c0 = ks >> 3;            // 0 or 4
            bf16x8 af[4], bfr[NFR];
            #pragma unroll
            for (int mi = 0; mi < 4; ++mi) {
                int row = wm * 64 + mi * 16 + (lane & 15);
                int cp  = (c0 + (lane >> 4)) ^ (lane & 7);
                af[mi] = *(const bf16x8*)&As[row * 64 + cp * 8];
            }
            #pragma unroll
            for (int nj = 0; nj < NFR; ++nj) {
                int row = wn * (TN / 2) + nj * 16 + (lane & 15);
                int cp  = (c0 + (lane >> 4)) ^ (lane & 7);
                bfr[nj] = *(const bf16x8*)&Bs[row * 64 + cp * 8];
            }
            #pragma unroll
            for (int mi = 0; mi < 4; ++mi)
                #pragma unroll
                for (int nj = 0; nj < NFR; ++nj)
                    acc[mi][nj] = __builtin_amdgcn_mfma_f32_16x16x32_bf16(af[mi], bfr[nj], acc[mi][nj], 0, 0, 0);
        }
        __syncthreads();
    }

    // epilogue: C/D layout col = lane&15, row = (lane>>4)*4 + reg
    #pragma unroll
    for (int mi = 0; mi < 4; ++mi) {
        #pragma unroll
        for (int nj = 0; nj < NFR; ++nj) {
            #pragma unroll
            for (int r = 0; r < 4; ++r) {
                int m = m0 + wm * 64 + mi * 16 + (lane >> 4) * 4 + r;
                int n = n0 + wn * (TN / 2) + nj * 16 + (lane & 15);
                float val = acc[mi][nj][r] + bias[n];
                if (Cf) {
                    Cf[(size_t)m * D_ + n] = val;
                } else {
                    int b = m >> 11, s = m & (S_ - 1);
                    int h = n >> 6,  d = n & 63;
                    C[((((size_t)b * H_ + h) * S_ + s) << 6) + d] = f2bf(val);
                }
            }
        }
    }
}

// ---------------- ELL build: LDS counters, zero global atomics --------------
// Grid (bh, dst-octant) = 32 x 8 blocks, 1024 threads. Each block scans all
// 32K edges of its bh (coalesced; 8x re-read is L2-absorbed) and claims only
// edges whose dst lies in its exclusive 256-node octant via LDS atomicAdd.
// ELL rows and deg entries of an octant are block-exclusive -> plain stores.
// Row order differs from atomic version; scatter-add is order-independent.
__global__ __launch_bounds__(1024) void build_ell(
    const int* __restrict__ start_nodes, const int* __restrict__ end_nodes,
    int* __restrict__ deg, unsigned short* __restrict__ ell)
{
    __shared__ int cnt[256];
    const int bh  = blockIdx.x >> 3;      // 0..31
    const int oct = blockIdx.x & 7;       // dst in [oct*256, oct*256+256)
    const int t   = threadIdx.x;
    const int dlo = oct << 8;
    if (t < 256) cnt[t] = 0;
    __syncthreads();

    const int base_idx = bh * (R_ * S_);
    for (int f = t; f < EPB; f += 1024) {   // 32 iterations
        int r2 = f >> 11;
        if (r2 == 0) continue;              // first-S flat entries masked
        int s = f & (S_ - 1);
        int r = r2 & 7;
        int idx = base_idx + r * S_ + s;
        int sn = start_nodes[idx];
        if (sn == -1) continue;             // padded edge
        int en = end_nodes[idx];
        int dst = (r2 < R_) ? en : sn;
        unsigned rel = (unsigned)(dst - dlo);
        if (rel < 256u) {
            int ki = (r2 < R_) ? sn : en;
            int pos = atomicAdd(&cnt[rel], 1);
            if (pos < ELLCAP)
                ell[((size_t)(bh * S_ + dst)) * ELLCAP + pos] =
                    (unsigned short)((r2 << 11) | ki);
        }
    }
    __syncthreads();
    if (t < 256) deg[bh * S_ + dlo + t] = cnt[t];
}

// ---------------- fused score+softmax+aggregate (R6 version — best) ---------
// One wave per dst node; 8 edges/iteration, 8 lanes/edge, 8 dk elems/lane
// (ushort8 = 16 B loads). ELL row prefetched once (row[lane]) and edges
// distributed via __shfl.
__global__ __launch_bounds__(256) void edge_gather(
    const unsigned short* __restrict__ q, const unsigned short* __restrict__ k_,
    const unsigned short* __restrict__ v_,
    const unsigned short* __restrict__ rel_q, const unsigned short* __restrict__ rel_k,
    const unsigned short* __restrict__ rel_v,
    const int* __restrict__ deg, const unsigned short* __restrict__ ell,
    unsigned short* __restrict__ attn)
{
    int raw = blockIdx.x;
    int xcd = raw & 7;
    int loc = raw >> 3;                 // 0..2047
    int bh  = xcd * 4 + (loc >> 9);     // 4 bh per XCD (k+v slice L2-resident)
    int wid = threadIdx.x >> 6;
    int dst = (loc & 511) * 4 + wid;
    int lane = threadIdx.x & 63;
    int grp = lane >> 3;                // edge slot within group-of-8
    int sub = lane & 7;                 // dk chunk (8 elems)
    int h = bh & 7;
    int g = bh * S_ + dst;
    size_t node_base = ((size_t)bh << 11);

    ushort8_t q8 = *(const ushort8_t*)&q[((node_base + dst) << 6) + sub * 8];
    float qv[8];
    #pragma unroll
    for (int i = 0; i < 8; ++i) qv[i] = bf2f(q8[i]);

    int n = deg[g];
    if (n > ELLCAP) n = ELLCAP;
    int d_all = (int)ell[(size_t)g * ELLCAP + lane];   // full row, 128 B coalesced

    float den = 0.f;
    float o[8] = {};
    #pragma unroll 2
    for (int j = 0; j < n; j += 8) {
        int slot = j + grp;
        int d = __shfl(d_all, slot);
        bool valid = slot < n;
        int ki = d & (S_ - 1);
        int r2 = (d >> 11) & 15;
        ushort8_t k8  = *(const ushort8_t*)&k_  [((node_base + ki) << 6) + sub * 8];
        ushort8_t rk8 = *(const ushort8_t*)&rel_k[(((h << 4) + r2) << 6) + sub * 8];
        ushort8_t rq8 = *(const ushort8_t*)&rel_q[(((h << 4) + r2) << 6) + sub * 8];
        float p = 0.f;
        #pragma unroll
        for (int i = 0; i < 8; ++i)
            p = fmaf(bf2f(k8[i]), qv[i] + bf2f(rq8[i]),
                     fmaf(qv[i], bf2f(rk8[i]), p));
        p += __shfl_xor(p, 1);
        p += __shfl_xor(p, 2);
        p += __shfl_xor(p, 4);
        float sf = valid ? __expf(p * (1.0f / 24.0f)) : 0.f;   // 3*sqrt(64)=24
        ushort8_t v8  = *(const ushort8_t*)&v_  [((node_base + ki) << 6) + sub * 8];
        ushort8_t rv8 = *(const ushort8_t*)&rel_v[(((h << 4) + r2) << 6) + sub * 8];
        den += sf;
        #pragma unroll
        for (int i = 0; i < 8; ++i)
            o[i] = fmaf(sf, bf2f(v8[i]) + bf2f(rv8[i]), o[i]);
    }
    // cross-group reduction (xor 8,16,32 preserves sub)
    den += __shfl_xor(den, 8); den += __shfl_xor(den, 16); den += __shfl_xor(den, 32);
    #pragma unroll
    for (int i = 0; i < 8; ++i) {
        o[i] += __shfl_xor(o[i], 8);
        o[i] += __shfl_xor(o[i], 16);
        o[i] += __shfl_xor(o[i], 32);
    }
    if (grp == 0) {
        float inv = (den > 0.f) ? 1.0f / den : 0.f;
        ushort8_t r;
        #pragma unroll
        for (int i = 0; i < 8; ++i) r[i] = f2bf(o[i] * inv);
        *(ushort8_t*)&attn[((node_base + dst) << 6) + sub * 8] = r;
    }
}

extern "C" void kernel_launch(void* const* d_in, const int* in_sizes, int n_in,
                              void* d_out, int out_size, void* d_ws, size_t ws_size,
                              hipStream_t stream) {
    const float* query = (const float*)d_in[0];
    const float* key   = (const float*)d_in[1];
    const float* value = (const float*)d_in[2];
    const int* start_nodes = (const int*)d_in[3];
    const int* end_nodes   = (const int*)d_in[4];
    const float* rel_q = (const float*)d_in[5];
    const float* rel_k = (const float*)d_in[6];
    const float* rel_v = (const float*)d_in[7];
    const float* Wq = (const float*)d_in[8];
    const float* bq = (const float*)d_in[9];
    const float* Wk = (const float*)d_in[10];
    const float* bk = (const float*)d_in[11];
    const float* Wv = (const float*)d_in[12];
    const float* bv = (const float*)d_in[13];
    const float* Wo = (const float*)d_in[14];
    const float* bo = (const float*)d_in[15];
    float* out = (float*)d_out;

    const size_t NQ = (size_t)B_ * H_ * S_ * DK_;   // 4,194,304
    const size_t NW = (size_t)D_ * D_;              // 262,144
    const size_t NR = (size_t)H_ * 2 * R_ * DK_;    // 8,192
    const size_t NG = (size_t)B_ * H_ * S_;         // 65,536 nodes
    unsigned short* p = (unsigned short*)d_ws;
    unsigned short* qc = p;            p += NQ;
    unsigned short* kc = p;            p += NQ;
    unsigned short* vc = p;            p += NQ;
    unsigned short* q  = p;            p += NQ;
    unsigned short* k  = p;            p += NQ;
    unsigned short* v  = p;            p += NQ;
    unsigned short* attn = p;          p += NQ;
    unsigned short* wqb = p;           p += NW;
    unsigned short* wkb = p;           p += NW;
    unsigned short* wvb = p;           p += NW;
    unsigned short* wob = p;           p += NW;
    unsigned short* rqb = p;           p += NR;
    unsigned short* rkb = p;           p += NR;
    unsigned short* rvb = p;           p += NR;
    unsigned short* ell = p;           p += NG * ELLCAP;   // 8 MB
    int* deg = (int*)p;

    // 1) fused converts (one dispatch; deg is written by build_ell, no memset)
    prep<<<13336, 256, 0, stream>>>(query, key, value, Wq, Wk, Wv, Wo,
                                    rel_q, rel_k, rel_v,
                                    qc, kc, vc, wqb, wkb, wvb, wob,
                                    rqb, rkb, rvb);

    // 2) ELL inversion (LDS counters, block-exclusive output regions)
    build_ell<<<B_ * H_ * 8, 1024, 0, stream>>>(start_nodes, end_nodes, deg, ell);

    // 3) fused QKV projection (128x128 tiles, 768 blocks)
    dim3 ggrid(B_ * S_ / 128, D_ / 128, 3);
    gemm_bf16<128><<<ggrid, 256, 0, stream>>>(qc, kc, vc, wqb, wkb, wvb, bq, bk, bv,
                                              q, k, v, nullptr, 0);

    // 4) fused attention (gather form, ELL)
    edge_gather<<<(B_ * H_ * S_) / 4, 256, 0, stream>>>(
        q, k, v, rqb, rkb, rvb, deg, ell, attn);

    // 5) output projection (128x64 tiles -> 512 blocks = 2/CU, fp32 out)
    dim3 ogrid(B_ * S_ / 128, D_ / 64, 1);
    gemm_bf16<64><<<ogrid, 256, 0, stream>>>(attn, attn, attn, wob, wob, wob, bo, bo, bo,
                                             nullptr, nullptr, nullptr, out, 1);
}

// Round 10
// 218.753 us; speedup vs baseline: 1.3954x; 1.0864x over previous
//
#include <hip/hip_runtime.h>
#include <math.h>

// Problem constants (fixed by reference): B=4, S=2048, D=512, H=8, R=8, dk=64
#define B_ 4
#define S_ 2048
#define D_ 512
#define H_ 8
#define R_ 8
#define DK_ 64
#define NEDGE (B_*H_*2*R_*S_)   // 1,048,576
#define EPB   (2*R_*S_)         // 32768 edges per (b,h)
#define ELLCAP 64               // max in-degree slots; Poisson(15) tail ~2e-8

typedef __attribute__((ext_vector_type(8))) short bf16x8;
typedef __attribute__((ext_vector_type(8))) unsigned short ushort8_t;
typedef __attribute__((ext_vector_type(4))) float f32x4;

#define AS1q const __attribute__((address_space(1)))
#define AS3q __attribute__((address_space(3)))

__device__ inline unsigned short f2bf(float f) {
    unsigned u = __builtin_bit_cast(unsigned, f);
    u += 0x7fffu + ((u >> 16) & 1u);   // RNE (no NaN inputs here)
    return (unsigned short)(u >> 16);
}
__device__ inline float bf2f(unsigned short u) {
    return __builtin_bit_cast(float, ((unsigned)u) << 16);
}

// ---------------- fused prep: qkv + W + rel converts ------------------------
__global__ __launch_bounds__(256) void prep(
    const float* __restrict__ query, const float* __restrict__ key,
    const float* __restrict__ value,
    const float* __restrict__ Wq, const float* __restrict__ Wk,
    const float* __restrict__ Wv, const float* __restrict__ Wo,
    const float* __restrict__ rel_q, const float* __restrict__ rel_k,
    const float* __restrict__ rel_v,
    unsigned short* __restrict__ qc, unsigned short* __restrict__ kc,
    unsigned short* __restrict__ vc,
    unsigned short* __restrict__ wqb, unsigned short* __restrict__ wkb,
    unsigned short* __restrict__ wvb, unsigned short* __restrict__ wob,
    unsigned short* __restrict__ rqb, unsigned short* __restrict__ rkb,
    unsigned short* __restrict__ rvb)
{
    int bid = blockIdx.x;
    const float* x;
    unsigned short* y;
    size_t i;
    if (bid < 12288) {
        int z = bid >> 12;                 // 0..2
        x = (z == 0) ? query : (z == 1) ? key : value;
        y = (z == 0) ? qc : (z == 1) ? kc : vc;
        i = ((size_t)(bid & 4095) * 256 + threadIdx.x) * 4;
    } else if (bid < 13312) {
        int r = bid - 12288;
        int z = r >> 8;                    // 0..3
        x = (z == 0) ? Wq : (z == 1) ? Wk : (z == 2) ? Wv : Wo;
        y = (z == 0) ? wqb : (z == 1) ? wkb : (z == 2) ? wvb : wob;
        i = ((size_t)(r & 255) * 256 + threadIdx.x) * 4;
    } else {
        int r = bid - 13312;               // 0..23
        int z = r >> 3;                    // 0..2
        x = (z == 0) ? rel_q : (z == 1) ? rel_k : rel_v;
        y = (z == 0) ? rqb : (z == 1) ? rkb : rvb;
        i = ((size_t)(r & 7) * 256 + threadIdx.x) * 4;
    }
    float4 v = *(const float4*)&x[i];
    *(ushort4*)&y[i] = make_ushort4(f2bf(v.x), f2bf(v.y), f2bf(v.z), f2bf(v.w));
}

// ---------------- bf16 GEMM, m97-style: global_load_lds + XOR-swizzled LDS --
template<int TN>
__global__ __launch_bounds__(256) void gemm_bf16(
    const unsigned short* __restrict__ A0, const unsigned short* __restrict__ A1,
    const unsigned short* __restrict__ A2,
    const unsigned short* __restrict__ W0, const unsigned short* __restrict__ W1,
    const unsigned short* __restrict__ W2,
    const float* __restrict__ bi0, const float* __restrict__ bi1, const float* __restrict__ bi2,
    unsigned short* __restrict__ C0, unsigned short* __restrict__ C1,
    unsigned short* __restrict__ C2,
    float* __restrict__ Cf, int a_bhsd)
{
    constexpr int NFR = TN / 32;           // B frags per wave (4 or 2)
    __shared__ unsigned short As[128 * 64];
    __shared__ unsigned short Bs[TN * 64];
    const int z = blockIdx.z;
    const unsigned short* A = (z == 0) ? A0 : (z == 1) ? A1 : A2;
    const unsigned short* W = (z == 0) ? W0 : (z == 1) ? W1 : W2;
    const float* bias        = (z == 0) ? bi0 : (z == 1) ? bi1 : bi2;
    unsigned short* C        = (z == 0) ? C0 : (z == 1) ? C1 : C2;

    const int t    = threadIdx.x;
    const int lane = t & 63;
    const int w    = t >> 6;
    const int wm   = w >> 1, wn = w & 1;
    const int m0   = blockIdx.x * 128;
    const int n0   = blockIdx.y * TN;

    const int lr    = lane >> 3;           // row within 8-row stage chunk
    const int cglob = (lane & 7) ^ lr;     // swizzled global source chunk

    f32x4 acc[4][NFR] = {};

    for (int kk = 0; kk < D_; kk += 64) {
        #pragma unroll
        for (int i = 0; i < 4; ++i) {
            int rowl = w * 32 + i * 8;         // wave-uniform LDS row base
            int m = m0 + rowl + lr;
            const unsigned short* ga;
            if (a_bhsd) {
                int b = m >> 11, s = m & (S_ - 1), h = kk >> 6;
                ga = A + ((((size_t)b * H_ + h) * S_ + s) << 6) + cglob * 8;
            } else {
                ga = A + (size_t)m * D_ + kk + cglob * 8;
            }
            __builtin_amdgcn_global_load_lds((AS1q unsigned*)ga,
                (AS3q unsigned*)(As + rowl * 64), 16, 0, 0);
        }
        #pragma unroll
        for (int i = 0; i < TN / 32; ++i) {
            int rowl = w * (TN / 4) + i * 8;
            const unsigned short* gb =
                W + (size_t)(n0 + rowl + lr) * D_ + kk + cglob * 8;
            __builtin_amdgcn_global_load_lds((AS1q unsigned*)gb,
                (AS3q unsigned*)(Bs + rowl * 64), 16, 0, 0);
        }
        __syncthreads();

        #pragma unroll
        for (int ks = 0; ks < 64; ks += 32) {
            const int c0 = ks >> 3;            // 0 or 4
            bf16x8 af[4], bfr[NFR];
            #pragma unroll
            for (int mi = 0; mi < 4; ++mi) {
                int row = wm * 64 + mi * 16 + (lane & 15);
                int cp  = (c0 + (lane >> 4)) ^ (lane & 7);
                af[mi] = *(const bf16x8*)&As[row * 64 + cp * 8];
            }
            #pragma unroll
            for (int nj = 0; nj < NFR; ++nj) {
                int row = wn * (TN / 2) + nj * 16 + (lane & 15);
                int cp  = (c0 + (lane >> 4)) ^ (lane & 7);
                bfr[nj] = *(const bf16x8*)&Bs[row * 64 + cp * 8];
            }
            #pragma unroll
            for (int mi = 0; mi < 4; ++mi)
                #pragma unroll
                for (int nj = 0; nj < NFR; ++nj)
                    acc[mi][nj] = __builtin_amdgcn_mfma_f32_16x16x32_bf16(af[mi], bfr[nj], acc[mi][nj], 0, 0, 0);
        }
        __syncthreads();
    }

    // epilogue: C/D layout col = lane&15, row = (lane>>4)*4 + reg
    #pragma unroll
    for (int mi = 0; mi < 4; ++mi) {
        #pragma unroll
        for (int nj = 0; nj < NFR; ++nj) {
            #pragma unroll
            for (int r = 0; r < 4; ++r) {
                int m = m0 + wm * 64 + mi * 16 + (lane >> 4) * 4 + r;
                int n = n0 + wn * (TN / 2) + nj * 16 + (lane & 15);
                float val = acc[mi][nj][r] + bias[n];
                if (Cf) {
                    Cf[(size_t)m * D_ + n] = val;
                } else {
                    int b = m >> 11, s = m & (S_ - 1);
                    int h = n >> 6,  d = n & 63;
                    C[((((size_t)b * H_ + h) * S_ + s) << 6) + d] = f2bf(val);
                }
            }
        }
    }
}

// ---------------- fused ELL-build + score+softmax+aggregate -----------------
// One block per (bh, 128-dst window): 1024 threads scan the bh's 32K edge
// slots, claim edges for their window via LDS counters into a 16 KB LDS ELL
// (never materialized in global), one barrier, then each of the 16 waves
// gathers 8 dst nodes with the R6-proven loop (8 edges/iter, 8 lanes/edge).
// XCD swizzle: blocks of bh land on one XCD -> edge-scan L2-shared, k/v
// slice (4 bh x 2 MB) L2-resident.
__global__ __launch_bounds__(1024) void attn_fused(
    const unsigned short* __restrict__ q, const unsigned short* __restrict__ k_,
    const unsigned short* __restrict__ v_,
    const unsigned short* __restrict__ rel_q, const unsigned short* __restrict__ rel_k,
    const unsigned short* __restrict__ rel_v,
    const int* __restrict__ start_nodes, const int* __restrict__ end_nodes,
    unsigned short* __restrict__ attn)
{
    __shared__ unsigned short ell[128 * ELLCAP];   // 16 KB
    __shared__ int cnt[128];
    const int bi  = blockIdx.x;          // 512 blocks
    const int xcd = bi & 7;
    const int loc = bi >> 3;             // 0..63
    const int bh  = xcd * 4 + (loc >> 4);
    const int dlo = (loc & 15) << 7;     // 128-dst window base
    const int t   = threadIdx.x;

    if (t < 128) cnt[t] = 0;
    __syncthreads();

    // ---- scan phase: coalesced read of this bh's edge lists ----
    const int base_idx = bh * (R_ * S_);
    for (int f = t; f < EPB; f += 1024) {   // 32 iterations
        int r2 = f >> 11;
        if (r2 == 0) continue;              // first-S flat entries masked
        int s = f & (S_ - 1);
        int idx = base_idx + (r2 & 7) * S_ + s;
        int sn = start_nodes[idx];
        if (sn == -1) continue;             // padded edge
        int en = end_nodes[idx];
        int dst = (r2 < R_) ? en : sn;
        unsigned rel = (unsigned)(dst - dlo);
        if (rel < 128u) {
            int ki = (r2 < R_) ? sn : en;
            int pos = atomicAdd(&cnt[rel], 1);
            if (pos < ELLCAP)
                ell[(rel << 6) + pos] = (unsigned short)((r2 << 11) | ki);
        }
    }
    __syncthreads();

    // ---- gather phase: wave w handles dsts dlo + dd*16 + w ----
    const int w    = t >> 6;
    const int lane = t & 63;
    const int grp  = lane >> 3;          // edge slot within group-of-8
    const int sub  = lane & 7;           // dk chunk (8 elems)
    const int h    = bh & 7;
    const size_t node_base = ((size_t)bh << 11);

    for (int dd = 0; dd < 8; ++dd) {
        int dl  = dd * 16 + w;           // 0..127
        int dst = dlo + dl;

        ushort8_t q8 = *(const ushort8_t*)&q[((node_base + dst) << 6) + sub * 8];
        float qv[8];
        #pragma unroll
        for (int i = 0; i < 8; ++i) qv[i] = bf2f(q8[i]);

        int n = cnt[dl];
        if (n > ELLCAP) n = ELLCAP;
        int d_all = (int)ell[(dl << 6) + lane];   // LDS row, 2-way free

        float den = 0.f;
        float o[8] = {};
        #pragma unroll 2
        for (int j = 0; j < n; j += 8) {
            int slot = j + grp;
            int d = __shfl(d_all, slot);
            bool valid = slot < n;
            int ki = d & (S_ - 1);
            int r2 = (d >> 11) & 15;
            ushort8_t k8  = *(const ushort8_t*)&k_  [((node_base + ki) << 6) + sub * 8];
            ushort8_t rk8 = *(const ushort8_t*)&rel_k[(((h << 4) + r2) << 6) + sub * 8];
            ushort8_t rq8 = *(const ushort8_t*)&rel_q[(((h << 4) + r2) << 6) + sub * 8];
            float p = 0.f;
            #pragma unroll
            for (int i = 0; i < 8; ++i)
                p = fmaf(bf2f(k8[i]), qv[i] + bf2f(rq8[i]),
                         fmaf(qv[i], bf2f(rk8[i]), p));
            p += __shfl_xor(p, 1);
            p += __shfl_xor(p, 2);
            p += __shfl_xor(p, 4);
            float sf = valid ? __expf(p * (1.0f / 24.0f)) : 0.f;   // 3*sqrt(64)=24
            ushort8_t v8  = *(const ushort8_t*)&v_  [((node_base + ki) << 6) + sub * 8];
            ushort8_t rv8 = *(const ushort8_t*)&rel_v[(((h << 4) + r2) << 6) + sub * 8];
            den += sf;
            #pragma unroll
            for (int i = 0; i < 8; ++i)
                o[i] = fmaf(sf, bf2f(v8[i]) + bf2f(rv8[i]), o[i]);
        }
        // cross-group reduction (xor 8,16,32 preserves sub)
        den += __shfl_xor(den, 8); den += __shfl_xor(den, 16); den += __shfl_xor(den, 32);
        #pragma unroll
        for (int i = 0; i < 8; ++i) {
            o[i] += __shfl_xor(o[i], 8);
            o[i] += __shfl_xor(o[i], 16);
            o[i] += __shfl_xor(o[i], 32);
        }
        if (grp == 0) {
            float inv = (den > 0.f) ? 1.0f / den : 0.f;
            ushort8_t r;
            #pragma unroll
            for (int i = 0; i < 8; ++i) r[i] = f2bf(o[i] * inv);
            *(ushort8_t*)&attn[((node_base + dst) << 6) + sub * 8] = r;
        }
    }
}

extern "C" void kernel_launch(void* const* d_in, const int* in_sizes, int n_in,
                              void* d_out, int out_size, void* d_ws, size_t ws_size,
                              hipStream_t stream) {
    const float* query = (const float*)d_in[0];
    const float* key   = (const float*)d_in[1];
    const float* value = (const float*)d_in[2];
    const int* start_nodes = (const int*)d_in[3];
    const int* end_nodes   = (const int*)d_in[4];
    const float* rel_q = (const float*)d_in[5];
    const float* rel_k = (const float*)d_in[6];
    const float* rel_v = (const float*)d_in[7];
    const float* Wq = (const float*)d_in[8];
    const float* bq = (const float*)d_in[9];
    const float* Wk = (const float*)d_in[10];
    const float* bk = (const float*)d_in[11];
    const float* Wv = (const float*)d_in[12];
    const float* bv = (const float*)d_in[13];
    const float* Wo = (const float*)d_in[14];
    const float* bo = (const float*)d_in[15];
    float* out = (float*)d_out;

    const size_t NQ = (size_t)B_ * H_ * S_ * DK_;   // 4,194,304
    const size_t NW = (size_t)D_ * D_;              // 262,144
    const size_t NR = (size_t)H_ * 2 * R_ * DK_;    // 8,192
    unsigned short* p = (unsigned short*)d_ws;
    unsigned short* qc = p;            p += NQ;
    unsigned short* kc = p;            p += NQ;
    unsigned short* vc = p;            p += NQ;
    unsigned short* q  = p;            p += NQ;
    unsigned short* k  = p;            p += NQ;
    unsigned short* v  = p;            p += NQ;
    unsigned short* attn = p;          p += NQ;
    unsigned short* wqb = p;           p += NW;
    unsigned short* wkb = p;           p += NW;
    unsigned short* wvb = p;           p += NW;
    unsigned short* wob = p;           p += NW;
    unsigned short* rqb = p;           p += NR;
    unsigned short* rkb = p;           p += NR;
    unsigned short* rvb = p;           p += NR;

    // 1) fused converts (one dispatch)
    prep<<<13336, 256, 0, stream>>>(query, key, value, Wq, Wk, Wv, Wo,
                                    rel_q, rel_k, rel_v,
                                    qc, kc, vc, wqb, wkb, wvb, wob,
                                    rqb, rkb, rvb);

    // 2) fused QKV projection (128x128 tiles, 768 blocks)
    dim3 ggrid(B_ * S_ / 128, D_ / 128, 3);
    gemm_bf16<128><<<ggrid, 256, 0, stream>>>(qc, kc, vc, wqb, wkb, wvb, bq, bk, bv,
                                              q, k, v, nullptr, 0);

    // 3) fused ELL-build + attention (no global ELL)
    attn_fused<<<512, 1024, 0, stream>>>(q, k, v, rqb, rkb, rvb,
                                         start_nodes, end_nodes, attn);

    // 4) output projection (128x64 tiles -> 512 blocks = 2/CU, fp32 out)
    dim3 ogrid(B_ * S_ / 128, D_ / 64, 1);
    gemm_bf16<64><<<ogrid, 256, 0, stream>>>(attn, attn, attn, wob, wob, wob, bo, bo, bo,
                                             nullptr, nullptr, nullptr, out, 1);
}